// Round 15
// baseline (210.631 us; speedup 1.0000x reference)
//
#include <hip/hip_runtime.h>

#define DIM 256
#define NSB 8
#define NLBL 64
#define NSEG (NSB * NLBL)
#define NBH 128   // histogram blocks
#define BPS 2     // blocks per segment in k_seg
#define CAP 288   // staged rows per k_seg block (LDS int8)
// dynamic LDS: xrows CAP*256B + muA 256*4 + wsum 8*4
#define SMEM_BYTES (CAP * 256 + DIM * 4 + 8 * 4)

// ---------------- k1: per-block histogram (plain stores) ----------------
__global__ void k_hist(const int* __restrict__ labels, const int* __restrict__ sbidx,
                       int* __restrict__ blockBins, int n) {
    __shared__ int bins[NSEG];
    for (int i = threadIdx.x; i < NSEG; i += 256) bins[i] = 0;
    __syncthreads();
    int t4 = blockIdx.x * 256 + threadIdx.x;
    int stride4 = gridDim.x * 256;
    for (int q = t4; q * 4 < n; q += stride4) {
        int4 lb = reinterpret_cast<const int4*>(labels)[q];
        int4 sb = reinterpret_cast<const int4*>(sbidx)[q];
        atomicAdd(&bins[sb.x * NLBL + lb.x], 1);
        atomicAdd(&bins[sb.y * NLBL + lb.y], 1);
        atomicAdd(&bins[sb.z * NLBL + lb.z], 1);
        atomicAdd(&bins[sb.w * NLBL + lb.w], 1);
    }
    __syncthreads();
    for (int i = threadIdx.x; i < NSEG; i += 256)
        blockBins[blockIdx.x * NSEG + i] = bins[i];
}

// ---------------- k2: reduce bins + scan + zero small accumulators ----------------
__global__ void k_scan(const int* __restrict__ blockBins, int* __restrict__ counts,
                       int* __restrict__ offsets, int* __restrict__ cursors,
                       float* __restrict__ Mvals, float* __restrict__ invcnt,
                       float* __restrict__ Lpull, float* __restrict__ pushv,
                       int* __restrict__ ticket) {
    __shared__ int cnt[NSEG];
    int t = threadIdx.x;          // 512 threads, one per segment
    int sum = 0;
    #pragma unroll 8
    for (int b = 0; b < NBH; b++) sum += blockBins[b * NSEG + t];
    cnt[t] = sum;
    counts[t] = sum;
    invcnt[t] = 1.0f / fmaxf((float)sum, 1.0f);
    if (t < NSB) { Lpull[t] = 0.f; pushv[t] = 0.f; }
    if (t == 0) ticket[0] = 0;    // re-zeroed every run: graph-replay-safe
    __syncthreads();
    if (t < 64) {                 // exclusive scan over 512 counts, one wave
        int lane = t;
        int carry = 0;
        for (int c = 0; c < NSB; c++) {
            int idx = c * 64 + lane;
            int v = cnt[idx];
            int incl = v;
            #pragma unroll
            for (int m = 1; m < 64; m <<= 1) {
                int t2 = __shfl_up(incl, m, 64);
                if (lane >= m) incl += t2;
            }
            int excl = carry + incl - v;
            offsets[idx] = excl;
            cursors[idx] = excl;
            carry += __shfl(incl, 63, 64);
            unsigned long long b = __ballot(v > 0);
            if (lane == 0) Mvals[c] = (float)__popcll(b);
        }
    }
}

// ---------------- k3: scatter point indices into sorted order ----------------
__global__ void k_scatter(const int* __restrict__ labels, const int* __restrict__ sbidx,
                          int* __restrict__ cursors, int* __restrict__ sorted, int n) {
    int t = blockIdx.x * blockDim.x + threadIdx.x;
    int stride = gridDim.x * blockDim.x;
    for (int q = t; q * 4 < n; q += stride) {
        int4 lb = reinterpret_cast<const int4*>(labels)[q];
        int4 sb = reinterpret_cast<const int4*>(sbidx)[q];
        int p = q * 4;
        sorted[atomicAdd(&cursors[sb.x * NLBL + lb.x], 1)] = p;
        sorted[atomicAdd(&cursors[sb.y * NLBL + lb.y], 1)] = p + 1;
        sorted[atomicAdd(&cursors[sb.z * NLBL + lb.z], 1)] = p + 2;
        sorted[atomicAdd(&cursors[sb.w * NLBL + lb.w], 1)] = p + 3;
    }
}

__device__ inline unsigned packq(float x, float y, float z, float w, float s) {
    int q0 = (int)rintf(x * s); q0 = max(-127, min(127, q0));
    int q1 = (int)rintf(y * s); q1 = max(-127, min(127, q1));
    int q2 = (int)rintf(z * s); q2 = max(-127, min(127, q2));
    int q3 = (int)rintf(w * s); q3 = max(-127, min(127, q3));
    return (unsigned)(q0 & 255) | ((unsigned)(q1 & 255) << 8) |
           ((unsigned)(q2 & 255) << 16) | ((unsigned)(q3 & 255) << 24);
}

// ------- k4: TWO 8-wave blocks per segment: gather+norm+mu partial (int8 LDS stage) then pull -------
__global__ __launch_bounds__(512) void k_seg(
    const float* __restrict__ outp, const int* __restrict__ sorted,
    const int* __restrict__ offsets, const int* __restrict__ counts,
    const float* __restrict__ invcnt, float* __restrict__ mu_sums,
    int* __restrict__ segdone, float* __restrict__ mus,
    float* __restrict__ Lpull) {
    extern __shared__ unsigned char smem[];
    unsigned* xrows = (unsigned*)smem;                   // CAP rows * 64 dwords
    float* muA  = (float*)(smem + CAP * 256);            // 256 (block-local accum -> mu)
    float* wsum = (float*)(smem + CAP * 256 + DIM * 4);  // 8
    __shared__ int segLast;

    int seg = blockIdx.x >> 1;       // BPS = 2
    int part = blockIdx.x & 1;
    int base = offsets[seg], cnt = counts[seg];
    int tid = threadIdx.x, lane = tid & 63, wv = tid >> 6;   // 8 waves
    float ic = invcnt[seg];
    if (tid < DIM) muA[tid] = 0.f;
    __syncthreads();
    if (cnt == 0) {
        if (part == 0 && tid < DIM) mus[(size_t)seg * DIM + tid] = 0.f;
        return;
    }
    int half = (cnt + 1) >> 1;
    int lo = part * half;                 // row range [lo, hi) within segment
    int hi = min(cnt, lo + half);
    int myN = hi - lo;                    // ≤ 288 = CAP (cnt ≤ ~576 w.h.p.; overflow handled below)

    // ---- Phase A: gather rows, normalize, accumulate mu partial, stage int8 into LDS ----
    float4 acc = {0.f, 0.f, 0.f, 0.f};
    int r = wv * 4;
    int p0 = (r + 0 < myN) ? sorted[base + lo + r + 0] : -1;
    int p1 = (r + 1 < myN) ? sorted[base + lo + r + 1] : -1;
    int p2 = (r + 2 < myN) ? sorted[base + lo + r + 2] : -1;
    int p3 = (r + 3 < myN) ? sorted[base + lo + r + 3] : -1;
    for (; r < myN; r += 32) {
        int nr = r + 32;
        int q0 = (nr + 0 < myN) ? sorted[base + lo + nr + 0] : -1;   // prefetch next ids
        int q1 = (nr + 1 < myN) ? sorted[base + lo + nr + 1] : -1;
        int q2 = (nr + 2 < myN) ? sorted[base + lo + nr + 2] : -1;
        int q3 = (nr + 3 < myN) ? sorted[base + lo + nr + 3] : -1;
        float4 v0 = {0.f,0.f,0.f,0.f}, v1 = {0.f,0.f,0.f,0.f};
        float4 v2 = {0.f,0.f,0.f,0.f}, v3 = {0.f,0.f,0.f,0.f};
        v0 = *reinterpret_cast<const float4*>(outp + (size_t)p0 * DIM + lane * 4);
        if (p1 >= 0) v1 = *reinterpret_cast<const float4*>(outp + (size_t)p1 * DIM + lane * 4);
        if (p2 >= 0) v2 = *reinterpret_cast<const float4*>(outp + (size_t)p2 * DIM + lane * 4);
        if (p3 >= 0) v3 = *reinterpret_cast<const float4*>(outp + (size_t)p3 * DIM + lane * 4);
        float s0 = v0.x*v0.x + v0.y*v0.y + v0.z*v0.z + v0.w*v0.w;
        float s1 = v1.x*v1.x + v1.y*v1.y + v1.z*v1.z + v1.w*v1.w;
        float s2 = v2.x*v2.x + v2.y*v2.y + v2.z*v2.z + v2.w*v2.w;
        float s3 = v3.x*v3.x + v3.y*v3.y + v3.z*v3.z + v3.w*v3.w;
        #pragma unroll
        for (int m = 32; m >= 1; m >>= 1) {   // 4 interleaved trees
            s0 += __shfl_xor(s0, m, 64);
            s1 += __shfl_xor(s1, m, 64);
            s2 += __shfl_xor(s2, m, 64);
            s3 += __shfl_xor(s3, m, 64);
        }
        float r0 = 1.0f / (sqrtf(s0) + 1e-8f);
        float r1 = 1.0f / (sqrtf(s1) + 1e-8f);
        float r2 = 1.0f / (sqrtf(s2) + 1e-8f);
        float r3 = 1.0f / (sqrtf(s3) + 1e-8f);
        if (r + 0 < CAP)            xrows[(r + 0) * 64 + lane] = packq(v0.x, v0.y, v0.z, v0.w, r0 * 256.f);
        if (p1 >= 0 && r + 1 < CAP) xrows[(r + 1) * 64 + lane] = packq(v1.x, v1.y, v1.z, v1.w, r1 * 256.f);
        if (p2 >= 0 && r + 2 < CAP) xrows[(r + 2) * 64 + lane] = packq(v2.x, v2.y, v2.z, v2.w, r2 * 256.f);
        if (p3 >= 0 && r + 3 < CAP) xrows[(r + 3) * 64 + lane] = packq(v3.x, v3.y, v3.z, v3.w, r3 * 256.f);
        acc.x += v0.x*r0 + v1.x*r1 + v2.x*r2 + v3.x*r3;   // invalid rows are zeros
        acc.y += v0.y*r0 + v1.y*r1 + v2.y*r2 + v3.y*r3;
        acc.z += v0.z*r0 + v1.z*r1 + v2.z*r2 + v3.z*r3;
        acc.w += v0.w*r0 + v1.w*r1 + v2.w*r2 + v3.w*r3;
        p0 = q0; p1 = q1; p2 = q2; p3 = q3;
    }
    atomicAdd(&muA[lane * 4 + 0], acc.x);
    atomicAdd(&muA[lane * 4 + 1], acc.y);
    atomicAdd(&muA[lane * 4 + 2], acc.z);
    atomicAdd(&muA[lane * 4 + 3], acc.w);
    __syncthreads();
    // combine the two partials through global mu_sums (ticket per segment)
    if (tid < DIM) atomicAdd(&mu_sums[(size_t)seg * DIM + tid], muA[tid]);
    __syncthreads();
    if (tid == 0) {
        __threadfence();
        segLast = (atomicAdd(&segdone[seg], 1) == BPS - 1) ? 1 : 0;
    }
    __syncthreads();
    if (segLast && tid < DIM)
        mus[(size_t)seg * DIM + tid] = atomicAdd(&mu_sums[(size_t)seg * DIM + tid], 0.f) * ic;
    __syncthreads();
    // spin-free mu for THIS block's phase B: read back combined sum (other block may lag;
    // poll until segdone shows both partials landed)
    if (tid == 0) {
        while (atomicAdd(&segdone[seg], 0) < BPS) { __builtin_amdgcn_s_sleep(8); }
        segLast = 1;
    }
    __syncthreads();
    if (tid < DIM)
        muA[tid] = atomicAdd(&mu_sums[(size_t)seg * DIM + tid], 0.f) * ic * 256.f;  // q units
    __syncthreads();

    // ---- Phase B: pull from LDS (int8), mu256 in registers ----
    float4 mu256 = *reinterpret_cast<const float4*>(muA + lane * 4);
    float psum = 0.f;
    int m1 = min(myN, CAP);
    for (int rr = wv * 4; rr < m1; rr += 32) {
        bool b1 = rr + 1 < m1, b2 = rr + 2 < m1, b3 = rr + 3 < m1;
        unsigned w0 = xrows[(rr + 0) * 64 + lane];
        unsigned w1 = b1 ? xrows[(rr + 1) * 64 + lane] : 0u;
        unsigned w2 = b2 ? xrows[(rr + 2) * 64 + lane] : 0u;
        unsigned w3 = b3 ? xrows[(rr + 3) * 64 + lane] : 0u;
        float d0 = fabsf(mu256.x - (float)((int)(w0 << 24) >> 24))
                 + fabsf(mu256.y - (float)((int)(w0 << 16) >> 24))
                 + fabsf(mu256.z - (float)((int)(w0 <<  8) >> 24))
                 + fabsf(mu256.w - (float)((int)w0 >> 24));
        float d1 = fabsf(mu256.x - (float)((int)(w1 << 24) >> 24))
                 + fabsf(mu256.y - (float)((int)(w1 << 16) >> 24))
                 + fabsf(mu256.z - (float)((int)(w1 <<  8) >> 24))
                 + fabsf(mu256.w - (float)((int)w1 >> 24));
        float d2 = fabsf(mu256.x - (float)((int)(w2 << 24) >> 24))
                 + fabsf(mu256.y - (float)((int)(w2 << 16) >> 24))
                 + fabsf(mu256.z - (float)((int)(w2 <<  8) >> 24))
                 + fabsf(mu256.w - (float)((int)w2 >> 24));
        float d3 = fabsf(mu256.x - (float)((int)(w3 << 24) >> 24))
                 + fabsf(mu256.y - (float)((int)(w3 << 16) >> 24))
                 + fabsf(mu256.z - (float)((int)(w3 <<  8) >> 24))
                 + fabsf(mu256.w - (float)((int)w3 >> 24));
        #pragma unroll
        for (int m = 32; m >= 1; m >>= 1) {   // 4 interleaved trees
            d0 += __shfl_xor(d0, m, 64);
            d1 += __shfl_xor(d1, m, 64);
            d2 += __shfl_xor(d2, m, 64);
            d3 += __shfl_xor(d3, m, 64);
        }
        float t0 = fmaxf(d0 * 0.00390625f - 0.5f, 0.f);   // /256, DELTA_V
        psum += t0 * t0;
        if (b1) { float t = fmaxf(d1 * 0.00390625f - 0.5f, 0.f); psum += t * t; }
        if (b2) { float t = fmaxf(d2 * 0.00390625f - 0.5f, 0.f); psum += t * t; }
        if (b3) { float t = fmaxf(d3 * 0.00390625f - 0.5f, 0.f); psum += t * t; }
    }
    // overflow rows (myN > CAP): re-gather from HBM, exact recompute (rare)
    for (int rr = CAP + wv; rr < myN; rr += 8) {
        int p = sorted[base + lo + rr];
        float4 v = *reinterpret_cast<const float4*>(outp + (size_t)p * DIM + lane * 4);
        float ss = v.x*v.x + v.y*v.y + v.z*v.z + v.w*v.w;
        #pragma unroll
        for (int m = 32; m >= 1; m >>= 1) ss += __shfl_xor(ss, m, 64);
        float rn = 1.0f / (sqrtf(ss) + 1e-8f);
        float d = fabsf(mu256.x * 0.00390625f - v.x*rn) + fabsf(mu256.y * 0.00390625f - v.y*rn)
                + fabsf(mu256.z * 0.00390625f - v.z*rn) + fabsf(mu256.w * 0.00390625f - v.w*rn);
        #pragma unroll
        for (int m = 32; m >= 1; m >>= 1) d += __shfl_xor(d, m, 64);
        float t = fmaxf(d - 0.5f, 0.f);
        psum += t * t;
    }
    if (lane == 0) wsum[wv] = psum;
    __syncthreads();
    if (tid == 0) {
        float tot = 0.f;
        #pragma unroll
        for (int w = 0; w < 8; w++) tot += wsum[w];
        atomicAdd(&Lpull[seg >> 6], tot * ic);
    }
}

// ---------------- k5: push (128 blocks) + ticketed final combine ----------------
__global__ void k_final(const float* __restrict__ mus, const int* __restrict__ counts,
                        float* __restrict__ pushv, float* __restrict__ Lpull,
                        const float* __restrict__ Mvals, int* __restrict__ ticket,
                        float* __restrict__ outv, int n) {
    __shared__ float lds[NLBL][DIM + 1];
    __shared__ float wsum[4];
    __shared__ int lastFlag;
    int s = blockIdx.x >> 4;
    int chunk = blockIdx.x & 15;
    for (int i = threadIdx.x; i < NLBL * DIM; i += 256) {
        int r = i >> 8, d = i & 255;
        lds[r][d] = mus[(size_t)(s * NLBL + r) * DIM + d];
    }
    __syncthreads();
    int pair = chunk * 256 + threadIdx.x;
    int l1 = pair >> 6, l2 = pair & 63;
    float dist = 0.0f;
    #pragma unroll 8
    for (int d = 0; d < DIM; d++) dist += fabsf(lds[l1][d] - lds[l2][d]);
    float v = fmaxf(3.0f - dist, 0.0f);   // 2*DELTA_D
    v = v * v;
    bool ok = (l1 != l2) && (counts[s * NLBL + l1] > 0) && (counts[s * NLBL + l2] > 0);
    v = ok ? v : 0.0f;
    #pragma unroll
    for (int m = 32; m >= 1; m >>= 1) v += __shfl_xor(v, m, 64);
    if ((threadIdx.x & 63) == 0) wsum[threadIdx.x >> 6] = v;
    __syncthreads();
    if (threadIdx.x == 0) {
        atomicAdd(&pushv[s], wsum[0] + wsum[1] + wsum[2] + wsum[3]);
        __threadfence();
        int t = atomicAdd(ticket, 1);
        lastFlag = (t == (int)gridDim.x - 1) ? 1 : 0;
    }
    __syncthreads();
    if (lastFlag && threadIdx.x == 0) {
        float loss = 0.0f;
        for (int q = 0; q < NSB; q++) {
            float M = Mvals[q];
            float pv = atomicAdd(&pushv[q], 0.0f);    // coherent cross-XCD read
            float lpv = atomicAdd(&Lpull[q], 0.0f);
            if (M > 1.0f)
                loss += lpv / M + pv / fmaxf(M * (M - 1.0f), 1.0f);
        }
        outv[0] = loss / (float)n;
    }
}

// tiny: zero mu_sums + segdone (graph-replay-safe, avoids a second memset node)
__global__ void k_zero(float* __restrict__ mu_sums, int* __restrict__ segdone) {
    int t = blockIdx.x * 256 + threadIdx.x;
    if (t < NSEG * DIM) mu_sums[t] = 0.f;
    if (t < NSEG) segdone[t] = 0;
}

extern "C" void kernel_launch(void* const* d_in, const int* in_sizes, int n_in,
                              void* d_out, int out_size, void* d_ws, size_t ws_size,
                              hipStream_t stream) {
    const float* outp = (const float*)d_in[0];
    const int* labels = (const int*)d_in[1];
    const int* sbidx = (const int*)d_in[2];
    float* outv = (float*)d_out;
    int n = in_sizes[1];

    // workspace layout
    float* mus = (float*)d_ws;                            // NSEG*DIM
    float* mu_sums = mus + (size_t)NSEG * DIM;            // NSEG*DIM  -- zeroed by k_zero
    int* segdone = (int*)(mu_sums + (size_t)NSEG * DIM);  // NSEG      -- zeroed by k_zero
    int* sorted = segdone + NSEG;                         // n
    int* blockBins = sorted + n;                          // NBH*NSEG
    int* counts = blockBins + NBH * NSEG;                 // 512
    int* offsets = counts + NSEG;                         // 512
    int* cursors = offsets + NSEG;                        // 512
    int* ticket = cursors + NSEG;                         // 1
    float* invcnt = (float*)(ticket + 1);                 // 512
    float* Mvals = invcnt + NSEG;                         // 8
    float* Lpull = Mvals + NSB;                           // 8
    float* pushv = Lpull + NSB;                           // 8

    hipFuncSetAttribute(reinterpret_cast<const void*>(k_seg),
                        hipFuncAttributeMaxDynamicSharedMemorySize, SMEM_BYTES);

    k_zero<<<(NSEG * DIM + 255) / 256, 256, 0, stream>>>(mu_sums, segdone);
    k_hist<<<NBH, 256, 0, stream>>>(labels, sbidx, blockBins, n);
    k_scan<<<1, 512, 0, stream>>>(blockBins, counts, offsets, cursors, Mvals, invcnt,
                                  Lpull, pushv, ticket);
    k_scatter<<<512, 256, 0, stream>>>(labels, sbidx, cursors, sorted, n);
    k_seg<<<NSEG * BPS, 512, SMEM_BYTES, stream>>>(outp, sorted, offsets, counts, invcnt,
                                                   mu_sums, segdone, mus, Lpull);
    k_final<<<NSB * 16, 256, 0, stream>>>(mus, counts, pushv, Lpull, Mvals,
                                          ticket, outv, n);
}

// Round 16
// 190.391 us; speedup vs baseline: 1.1063x; 1.1063x over previous
//
#include <hip/hip_runtime.h>

#define DIM 256
#define NSB 8
#define NLBL 64
#define NSEG (NSB * NLBL)
#define NBH 128   // histogram blocks
#define CAP 576   // staged rows per segment (LDS int8)
// dynamic LDS: xrows CAP*256B + muA 256*4 + wsum 16*4
#define SMEM_BYTES (CAP * 256 + DIM * 4 + 16 * 4)

// ---------------- k1: per-block histogram (plain stores) ----------------
__global__ void k_hist(const int* __restrict__ labels, const int* __restrict__ sbidx,
                       int* __restrict__ blockBins, int n) {
    __shared__ int bins[NSEG];
    for (int i = threadIdx.x; i < NSEG; i += 256) bins[i] = 0;
    __syncthreads();
    int t4 = blockIdx.x * 256 + threadIdx.x;
    int stride4 = gridDim.x * 256;
    for (int q = t4; q * 4 < n; q += stride4) {
        int4 lb = reinterpret_cast<const int4*>(labels)[q];
        int4 sb = reinterpret_cast<const int4*>(sbidx)[q];
        atomicAdd(&bins[sb.x * NLBL + lb.x], 1);
        atomicAdd(&bins[sb.y * NLBL + lb.y], 1);
        atomicAdd(&bins[sb.z * NLBL + lb.z], 1);
        atomicAdd(&bins[sb.w * NLBL + lb.w], 1);
    }
    __syncthreads();
    for (int i = threadIdx.x; i < NSEG; i += 256)
        blockBins[blockIdx.x * NSEG + i] = bins[i];
}

// ---------------- k2: reduce bins + scan + zero small accumulators ----------------
__global__ void k_scan(const int* __restrict__ blockBins, int* __restrict__ counts,
                       int* __restrict__ offsets, int* __restrict__ cursors,
                       float* __restrict__ Mvals, float* __restrict__ invcnt,
                       float* __restrict__ Lpull, float* __restrict__ pushv,
                       int* __restrict__ ticket) {
    __shared__ int cnt[NSEG];
    int t = threadIdx.x;          // 512 threads, one per segment
    int sum = 0;
    #pragma unroll 4
    for (int b = 0; b < NBH; b++) sum += blockBins[b * NSEG + t];
    cnt[t] = sum;
    counts[t] = sum;
    invcnt[t] = 1.0f / fmaxf((float)sum, 1.0f);
    if (t < NSB) { Lpull[t] = 0.f; pushv[t] = 0.f; }
    if (t == 0) ticket[0] = 0;    // re-zeroed every run: graph-replay-safe
    __syncthreads();
    if (t < 64) {                 // exclusive scan over 512 counts, one wave
        int lane = t;
        int carry = 0;
        for (int c = 0; c < NSB; c++) {
            int idx = c * 64 + lane;
            int v = cnt[idx];
            int incl = v;
            #pragma unroll
            for (int m = 1; m < 64; m <<= 1) {
                int t2 = __shfl_up(incl, m, 64);
                if (lane >= m) incl += t2;
            }
            int excl = carry + incl - v;
            offsets[idx] = excl;
            cursors[idx] = excl;
            carry += __shfl(incl, 63, 64);
            unsigned long long b = __ballot(v > 0);
            if (lane == 0) Mvals[c] = (float)__popcll(b);
        }
    }
}

// ---------------- k3: scatter point indices into sorted order ----------------
__global__ void k_scatter(const int* __restrict__ labels, const int* __restrict__ sbidx,
                          int* __restrict__ cursors, int* __restrict__ sorted, int n) {
    int t = blockIdx.x * blockDim.x + threadIdx.x;
    int stride = gridDim.x * blockDim.x;
    for (int q = t; q * 4 < n; q += stride) {
        int4 lb = reinterpret_cast<const int4*>(labels)[q];
        int4 sb = reinterpret_cast<const int4*>(sbidx)[q];
        int p = q * 4;
        sorted[atomicAdd(&cursors[sb.x * NLBL + lb.x], 1)] = p;
        sorted[atomicAdd(&cursors[sb.y * NLBL + lb.y], 1)] = p + 1;
        sorted[atomicAdd(&cursors[sb.z * NLBL + lb.z], 1)] = p + 2;
        sorted[atomicAdd(&cursors[sb.w * NLBL + lb.w], 1)] = p + 3;
    }
}

__device__ inline unsigned packq(float x, float y, float z, float w, float s) {
    int q0 = (int)rintf(x * s); q0 = max(-127, min(127, q0));
    int q1 = (int)rintf(y * s); q1 = max(-127, min(127, q1));
    int q2 = (int)rintf(z * s); q2 = max(-127, min(127, q2));
    int q3 = (int)rintf(w * s); q3 = max(-127, min(127, q3));
    return (unsigned)(q0 & 255) | ((unsigned)(q1 & 255) << 8) |
           ((unsigned)(q2 & 255) << 16) | ((unsigned)(q3 & 255) << 24);
}

// ------- k4: ONE 16-wave block per segment: gather+norm+mu (int8 LDS stage) then pull -------
__global__ __launch_bounds__(1024) void k_seg(
    const float* __restrict__ outp, const int* __restrict__ sorted,
    const int* __restrict__ offsets, const int* __restrict__ counts,
    const float* __restrict__ invcnt, float* __restrict__ mus,
    float* __restrict__ Lpull) {
    extern __shared__ unsigned char smem[];
    unsigned* xrows = (unsigned*)smem;                   // CAP rows * 64 dwords
    float* muA  = (float*)(smem + CAP * 256);            // 256 (atomic accum -> mu)
    float* wsum = (float*)(smem + CAP * 256 + DIM * 4);  // 16

    int seg = blockIdx.x;
    int base = offsets[seg], cnt = counts[seg];
    int tid = threadIdx.x, lane = tid & 63, wv = tid >> 6;   // 16 waves
    float ic = invcnt[seg];
    if (tid < DIM) muA[tid] = 0.f;
    __syncthreads();
    if (cnt == 0) {
        if (tid < DIM) mus[(size_t)seg * DIM + tid] = 0.f;
        return;
    }

    // ---- Phase A: gather rows, normalize, accumulate mu, stage int8 into LDS ----
    float4 acc = {0.f, 0.f, 0.f, 0.f};
    int r = wv * 4;
    int p0 = (r + 0 < cnt) ? sorted[base + r + 0] : -1;
    int p1 = (r + 1 < cnt) ? sorted[base + r + 1] : -1;
    int p2 = (r + 2 < cnt) ? sorted[base + r + 2] : -1;
    int p3 = (r + 3 < cnt) ? sorted[base + r + 3] : -1;
    for (; r < cnt; r += 64) {
        int nr = r + 64;
        int q0 = (nr + 0 < cnt) ? sorted[base + nr + 0] : -1;   // prefetch next ids
        int q1 = (nr + 1 < cnt) ? sorted[base + nr + 1] : -1;
        int q2 = (nr + 2 < cnt) ? sorted[base + nr + 2] : -1;
        int q3 = (nr + 3 < cnt) ? sorted[base + nr + 3] : -1;
        float4 v0 = {0.f,0.f,0.f,0.f}, v1 = {0.f,0.f,0.f,0.f};
        float4 v2 = {0.f,0.f,0.f,0.f}, v3 = {0.f,0.f,0.f,0.f};
        v0 = *reinterpret_cast<const float4*>(outp + (size_t)p0 * DIM + lane * 4);
        if (p1 >= 0) v1 = *reinterpret_cast<const float4*>(outp + (size_t)p1 * DIM + lane * 4);
        if (p2 >= 0) v2 = *reinterpret_cast<const float4*>(outp + (size_t)p2 * DIM + lane * 4);
        if (p3 >= 0) v3 = *reinterpret_cast<const float4*>(outp + (size_t)p3 * DIM + lane * 4);
        float s0 = v0.x*v0.x + v0.y*v0.y + v0.z*v0.z + v0.w*v0.w;
        float s1 = v1.x*v1.x + v1.y*v1.y + v1.z*v1.z + v1.w*v1.w;
        float s2 = v2.x*v2.x + v2.y*v2.y + v2.z*v2.z + v2.w*v2.w;
        float s3 = v3.x*v3.x + v3.y*v3.y + v3.z*v3.z + v3.w*v3.w;
        #pragma unroll
        for (int m = 32; m >= 1; m >>= 1) {   // 4 interleaved trees
            s0 += __shfl_xor(s0, m, 64);
            s1 += __shfl_xor(s1, m, 64);
            s2 += __shfl_xor(s2, m, 64);
            s3 += __shfl_xor(s3, m, 64);
        }
        float r0 = 1.0f / (sqrtf(s0) + 1e-8f);
        float r1 = 1.0f / (sqrtf(s1) + 1e-8f);
        float r2 = 1.0f / (sqrtf(s2) + 1e-8f);
        float r3 = 1.0f / (sqrtf(s3) + 1e-8f);
        // stage int8 rows (scale 256 folded into rn)
        if (r + 0 < CAP)            xrows[(r + 0) * 64 + lane] = packq(v0.x, v0.y, v0.z, v0.w, r0 * 256.f);
        if (p1 >= 0 && r + 1 < CAP) xrows[(r + 1) * 64 + lane] = packq(v1.x, v1.y, v1.z, v1.w, r1 * 256.f);
        if (p2 >= 0 && r + 2 < CAP) xrows[(r + 2) * 64 + lane] = packq(v2.x, v2.y, v2.z, v2.w, r2 * 256.f);
        if (p3 >= 0 && r + 3 < CAP) xrows[(r + 3) * 64 + lane] = packq(v3.x, v3.y, v3.z, v3.w, r3 * 256.f);
        acc.x += v0.x*r0 + v1.x*r1 + v2.x*r2 + v3.x*r3;   // invalid rows are zeros
        acc.y += v0.y*r0 + v1.y*r1 + v2.y*r2 + v3.y*r3;
        acc.z += v0.z*r0 + v1.z*r1 + v2.z*r2 + v3.z*r3;
        acc.w += v0.w*r0 + v1.w*r1 + v2.w*r2 + v3.w*r3;
        p0 = q0; p1 = q1; p2 = q2; p3 = q3;
    }
    // LDS-atomic mu reduction (16 adds per address)
    atomicAdd(&muA[lane * 4 + 0], acc.x);
    atomicAdd(&muA[lane * 4 + 1], acc.y);
    atomicAdd(&muA[lane * 4 + 2], acc.z);
    atomicAdd(&muA[lane * 4 + 3], acc.w);
    __syncthreads();
    if (tid < DIM) {
        float mu = muA[tid] * ic;
        muA[tid] = mu;
        mus[(size_t)seg * DIM + tid] = mu;   // for the push kernel
    }
    __syncthreads();

    // ---- Phase B: pull from LDS (int8), mu in registers ----
    float4 mu4 = *reinterpret_cast<const float4*>(muA + lane * 4);
    float4 mu256 = {mu4.x * 256.f, mu4.y * 256.f, mu4.z * 256.f, mu4.w * 256.f};
    float psum = 0.f;
    int m1 = min(cnt, CAP);
    for (int rr = wv * 4; rr < m1; rr += 64) {
        bool b1 = rr + 1 < m1, b2 = rr + 2 < m1, b3 = rr + 3 < m1;
        unsigned w0 = xrows[(rr + 0) * 64 + lane];
        unsigned w1 = b1 ? xrows[(rr + 1) * 64 + lane] : 0u;
        unsigned w2 = b2 ? xrows[(rr + 2) * 64 + lane] : 0u;
        unsigned w3 = b3 ? xrows[(rr + 3) * 64 + lane] : 0u;
        float d0 = fabsf(mu256.x - (float)((int)(w0 << 24) >> 24))
                 + fabsf(mu256.y - (float)((int)(w0 << 16) >> 24))
                 + fabsf(mu256.z - (float)((int)(w0 <<  8) >> 24))
                 + fabsf(mu256.w - (float)((int)w0 >> 24));
        float d1 = fabsf(mu256.x - (float)((int)(w1 << 24) >> 24))
                 + fabsf(mu256.y - (float)((int)(w1 << 16) >> 24))
                 + fabsf(mu256.z - (float)((int)(w1 <<  8) >> 24))
                 + fabsf(mu256.w - (float)((int)w1 >> 24));
        float d2 = fabsf(mu256.x - (float)((int)(w2 << 24) >> 24))
                 + fabsf(mu256.y - (float)((int)(w2 << 16) >> 24))
                 + fabsf(mu256.z - (float)((int)(w2 <<  8) >> 24))
                 + fabsf(mu256.w - (float)((int)w2 >> 24));
        float d3 = fabsf(mu256.x - (float)((int)(w3 << 24) >> 24))
                 + fabsf(mu256.y - (float)((int)(w3 << 16) >> 24))
                 + fabsf(mu256.z - (float)((int)(w3 <<  8) >> 24))
                 + fabsf(mu256.w - (float)((int)w3 >> 24));
        #pragma unroll
        for (int m = 32; m >= 1; m >>= 1) {   // 4 interleaved trees
            d0 += __shfl_xor(d0, m, 64);
            d1 += __shfl_xor(d1, m, 64);
            d2 += __shfl_xor(d2, m, 64);
            d3 += __shfl_xor(d3, m, 64);
        }
        float t0 = fmaxf(d0 * 0.00390625f - 0.5f, 0.f);   // /256, DELTA_V
        psum += t0 * t0;
        if (b1) { float t = fmaxf(d1 * 0.00390625f - 0.5f, 0.f); psum += t * t; }
        if (b2) { float t = fmaxf(d2 * 0.00390625f - 0.5f, 0.f); psum += t * t; }
        if (b3) { float t = fmaxf(d3 * 0.00390625f - 0.5f, 0.f); psum += t * t; }
    }
    // overflow rows (cnt > CAP): re-gather from HBM, exact recompute (rare)
    for (int rr = CAP + wv; rr < cnt; rr += 16) {
        int p = sorted[base + rr];
        float4 v = *reinterpret_cast<const float4*>(outp + (size_t)p * DIM + lane * 4);
        float ss = v.x*v.x + v.y*v.y + v.z*v.z + v.w*v.w;
        #pragma unroll
        for (int m = 32; m >= 1; m >>= 1) ss += __shfl_xor(ss, m, 64);
        float rn = 1.0f / (sqrtf(ss) + 1e-8f);
        float d = fabsf(mu4.x - v.x*rn) + fabsf(mu4.y - v.y*rn)
                + fabsf(mu4.z - v.z*rn) + fabsf(mu4.w - v.w*rn);
        #pragma unroll
        for (int m = 32; m >= 1; m >>= 1) d += __shfl_xor(d, m, 64);
        float t = fmaxf(d - 0.5f, 0.f);
        psum += t * t;
    }
    if (lane == 0) wsum[wv] = psum;
    __syncthreads();
    if (tid == 0) {
        float tot = 0.f;
        #pragma unroll
        for (int w = 0; w < 16; w++) tot += wsum[w];
        atomicAdd(&Lpull[seg >> 6], tot * ic);
    }
}

// ---------------- k5: push (128 blocks) + ticketed final combine ----------------
__global__ void k_final(const float* __restrict__ mus, const int* __restrict__ counts,
                        float* __restrict__ pushv, float* __restrict__ Lpull,
                        const float* __restrict__ Mvals, int* __restrict__ ticket,
                        float* __restrict__ outv, int n) {
    __shared__ float lds[NLBL][DIM + 1];
    __shared__ float wsum[4];
    __shared__ int lastFlag;
    int s = blockIdx.x >> 4;
    int chunk = blockIdx.x & 15;
    for (int i = threadIdx.x; i < NLBL * DIM; i += 256) {
        int r = i >> 8, d = i & 255;
        lds[r][d] = mus[(size_t)(s * NLBL + r) * DIM + d];
    }
    __syncthreads();
    int pair = chunk * 256 + threadIdx.x;
    int l1 = pair >> 6, l2 = pair & 63;
    float dist = 0.0f;
    #pragma unroll 8
    for (int d = 0; d < DIM; d++) dist += fabsf(lds[l1][d] - lds[l2][d]);
    float v = fmaxf(3.0f - dist, 0.0f);   // 2*DELTA_D
    v = v * v;
    bool ok = (l1 != l2) && (counts[s * NLBL + l1] > 0) && (counts[s * NLBL + l2] > 0);
    v = ok ? v : 0.0f;
    #pragma unroll
    for (int m = 32; m >= 1; m >>= 1) v += __shfl_xor(v, m, 64);
    if ((threadIdx.x & 63) == 0) wsum[threadIdx.x >> 6] = v;
    __syncthreads();
    if (threadIdx.x == 0) {
        atomicAdd(&pushv[s], wsum[0] + wsum[1] + wsum[2] + wsum[3]);
        __threadfence();
        int t = atomicAdd(ticket, 1);
        lastFlag = (t == (int)gridDim.x - 1) ? 1 : 0;
    }
    __syncthreads();
    if (lastFlag && threadIdx.x == 0) {
        float loss = 0.0f;
        for (int q = 0; q < NSB; q++) {
            float M = Mvals[q];
            float pv = atomicAdd(&pushv[q], 0.0f);    // coherent cross-XCD read
            float lpv = atomicAdd(&Lpull[q], 0.0f);
            if (M > 1.0f)
                loss += lpv / M + pv / fmaxf(M * (M - 1.0f), 1.0f);
        }
        outv[0] = loss / (float)n;
    }
}

extern "C" void kernel_launch(void* const* d_in, const int* in_sizes, int n_in,
                              void* d_out, int out_size, void* d_ws, size_t ws_size,
                              hipStream_t stream) {
    const float* outp = (const float*)d_in[0];
    const int* labels = (const int*)d_in[1];
    const int* sbidx = (const int*)d_in[2];
    float* outv = (float*)d_out;
    int n = in_sizes[1];

    // workspace layout
    float* mus = (float*)d_ws;                            // NSEG*DIM
    int* sorted = (int*)(mus + (size_t)NSEG * DIM);       // n
    int* blockBins = sorted + n;                          // NBH*NSEG
    int* counts = blockBins + NBH * NSEG;                 // 512
    int* offsets = counts + NSEG;                         // 512
    int* cursors = offsets + NSEG;                        // 512
    int* ticket = cursors + NSEG;                         // 1
    float* invcnt = (float*)(ticket + 1);                 // 512
    float* Mvals = invcnt + NSEG;                         // 8
    float* Lpull = Mvals + NSB;                           // 8
    float* pushv = Lpull + NSB;                           // 8

    hipFuncSetAttribute(reinterpret_cast<const void*>(k_seg),
                        hipFuncAttributeMaxDynamicSharedMemorySize, SMEM_BYTES);

    k_hist<<<NBH, 256, 0, stream>>>(labels, sbidx, blockBins, n);
    k_scan<<<1, 512, 0, stream>>>(blockBins, counts, offsets, cursors, Mvals, invcnt,
                                  Lpull, pushv, ticket);
    k_scatter<<<256, 256, 0, stream>>>(labels, sbidx, cursors, sorted, n);
    k_seg<<<NSEG, 1024, SMEM_BYTES, stream>>>(outp, sorted, offsets, counts, invcnt,
                                              mus, Lpull);
    k_final<<<NSB * 16, 256, 0, stream>>>(mus, counts, pushv, Lpull, Mvals,
                                          ticket, outv, n);
}